// Round 5
// baseline (1741.890 us; speedup 1.0000x reference)
//
#include <hip/hip_runtime.h>
#include <hip/hip_fp16.h>
#include <stdint.h>

#define B_TOTAL 1024
#define T_TOTAL 1024
#define LOG2E 1.44269504088896f

typedef _Float16 f16x2 __attribute__((ext_vector_type(2)));

__device__ __forceinline__ float dot2acc(uint32_t xw, f16x2 w, float acc) {
#if __has_builtin(__builtin_amdgcn_fdot2)
    return __builtin_amdgcn_fdot2(__builtin_bit_cast(f16x2, xw), w, acc, false);
#else
    f16x2 xv = __builtin_bit_cast(f16x2, xw);
    return acc + (float)xv.x * (float)w.x + (float)xv.y * (float)w.y;
#endif
}

__device__ __forceinline__ uint32_t packf2(float a, float b) {
    f16x2 t;
    t.x = (_Float16)a;
    t.y = (_Float16)b;
    return __builtin_bit_cast(uint32_t, t);
}

__device__ __forceinline__ float sigm_(float z) {
    float e = __builtin_amdgcn_exp2f(-LOG2E * z);
    return __builtin_amdgcn_rcpf(1.0f + e);
}
__device__ __forceinline__ float tanh_(float z) {
    float e = __builtin_amdgcn_exp2f((2.0f * LOG2E) * z);
    float r = __builtin_amdgcn_rcpf(1.0f + e);
    return __builtin_fmaf(-2.0f, r, 1.0f);
}

__device__ __forceinline__ void wavebar() {
#if __has_builtin(__builtin_amdgcn_wave_barrier)
    __builtin_amdgcn_wave_barrier();
#endif
}

// ======================= FAST PATH =======================
// gates_gemm: fully-parallel preactivation pass.
// out gbuf[(t*B+b)*NG + c] where c = dir*2H + 2*j + p : dword p of unit j =
//   p==0 -> (i,f) gates, p==1 -> (g,o) gates, f16x2, bias folded in.
// Thread owns column c (weights for 2 gate rows in regs), strides over (t,b).
template <int D, int H, int NDIR, bool LAYER1>
__global__ void __launch_bounds__(320) gates_gemm(
    const float* __restrict__ x,              // LAYER1: [B][T][8] f32
    const __half* __restrict__ inact,         // else: [T*B][D] f16
    const float* __restrict__ wf, const float* __restrict__ bfi, const float* __restrict__ bfh,
    const float* __restrict__ wb, const float* __restrict__ bbi, const float* __restrict__ bbh,
    uint32_t* __restrict__ gbuf)
{
    constexpr int NG  = NDIR * 2 * H;   // dwords per (t,b)
    constexpr int YS  = 320 / NG;       // row-streams per block (4/8/16)
    constexpr int NDW = D / 2;

    const int tid = threadIdx.x;
    const int c   = tid % NG;
    const int s   = tid / NG;
    const int dir = c / (2 * H);
    const int rem = c % (2 * H);
    const int j   = rem >> 1;
    const int p   = rem & 1;
    const int r0  = p * 2 * H + j;      // rows: p0 -> (i=j, f=H+j); p1 -> (g=2H+j, o=3H+j)
    const int r1  = r0 + H;

    const float* w  = (NDIR == 2 && dir) ? wb : wf;
    const float* bi = (NDIR == 2 && dir) ? bbi : bfi;
    const float* bh = (NDIR == 2 && dir) ? bbh : bfh;

    f16x2 w0[NDW], w1[NDW];
#pragma unroll
    for (int d = 0; d < NDW; ++d) {
        f16x2 t0, t1;
        t0.x = (_Float16)w[r0 * D + 2 * d];
        t0.y = (_Float16)w[r0 * D + 2 * d + 1];
        t1.x = (_Float16)w[r1 * D + 2 * d];
        t1.y = (_Float16)w[r1 * D + 2 * d + 1];
        w0[d] = t0;
        w1[d] = t1;
    }
    const float bias0 = bi[r0] + bh[r0];
    const float bias1 = bi[r1] + bh[r1];

    const int TB = T_TOTAL * B_TOTAL;
    for (int tb = blockIdx.x * YS + s; tb < TB; tb += gridDim.x * YS) {
        uint32_t xr[NDW];
        if constexpr (LAYER1) {
            const int t = tb >> 10;         // tb / B
            const int b = tb & 1023;        // tb % B
            const float* xp = x + ((size_t)b * T_TOTAL + t) * 8;
            float4 f0 = ((const float4*)xp)[0];
            float4 f1 = ((const float4*)xp)[1];
            float4 l0 = {0, 0, 0, 0}, l1 = {0, 0, 0, 0};
            if (t > 0) {
                l0 = ((const float4*)(xp - 8))[0];
                l1 = ((const float4*)(xp - 8))[1];
            }
            xr[0] = packf2(f0.x, f0.y); xr[1] = packf2(f0.z, f0.w);
            xr[2] = packf2(f1.x, f1.y); xr[3] = packf2(f1.z, f1.w);
            xr[4] = packf2(l0.x, l0.y); xr[5] = packf2(l0.z, l0.w);
            xr[6] = packf2(l1.x, l1.y); xr[7] = packf2(l1.z, l1.w);
        } else {
            const uint32_t* ip = (const uint32_t*)inact + (size_t)tb * NDW;
            if constexpr ((NDW % 4) == 0) {
#pragma unroll
                for (int q4 = 0; q4 < NDW / 4; ++q4) {
                    uint4 v = ((const uint4*)ip)[q4];
                    xr[4 * q4] = v.x; xr[4 * q4 + 1] = v.y;
                    xr[4 * q4 + 2] = v.z; xr[4 * q4 + 3] = v.w;
                }
            } else {
#pragma unroll
                for (int q2 = 0; q2 < NDW / 2; ++q2) {
                    uint2 v = ((const uint2*)ip)[q2];
                    xr[2 * q2] = v.x; xr[2 * q2 + 1] = v.y;
                }
                if constexpr (NDW & 1) xr[NDW - 1] = ip[NDW - 1];
            }
        }

        float d0 = bias0, d1 = bias1;
#pragma unroll
        for (int d = 0; d < NDW; ++d) {
            d0 = dot2acc(xr[d], w0[d], d0);
            d1 = dot2acc(xr[d], w1[d], d1);
        }
        gbuf[(size_t)tb * NG + c] = packf2(d0, d1);
    }
}

// Slim scan: only h·W_hh in the loop. Lane = (group g, unit j), all 4 gates
// per lane, single wave, no __syncthreads. Live set ~80 regs (no remat).
template <int H, int NDIR, bool STORE_ALL>
__global__ void __launch_bounds__(64, 1) lstm_scan2(
    const uint32_t* __restrict__ gbuf,        // [T*B][NG] dw
    const float* __restrict__ whhf, const float* __restrict__ whhb,
    __half* __restrict__ outact,              // STORE_ALL: [T][B][2H] f16
    float* __restrict__ lasth)                // !STORE_ALL: [B][H] f32
{
    constexpr int GPW   = 64 / H;
    constexpr int NH    = H / 2;
    constexpr int NG    = NDIR * 2 * H;
    constexpr int HS_DW = (H == 20) ? 12 : 8;

    const int dir  = (NDIR == 2) ? blockIdx.y : 0;
    const int lane = threadIdx.x;
    const int g    = lane / H;
    const int j    = lane - g * H;
    const int b    = blockIdx.x * GPW + g;
    const bool valid = (g < GPW) && (b < B_TOTAL);
    const int bs   = valid ? b : (B_TOTAL - 1);

    const float* w_hh = dir ? whhb : whhf;

    __shared__ uint32_t hsm[GPW + 1][HS_DW];

    f16x2 whh2[4][NH];
#pragma unroll
    for (int q = 0; q < 4; ++q) {
        const int r = q * H + j;
#pragma unroll
        for (int k = 0; k < NH; ++k) {
            f16x2 t;
            t.x = (_Float16)w_hh[r * H + 2 * k];
            t.y = (_Float16)w_hh[r * H + 2 * k + 1];
            whh2[q][k] = t;
        }
    }

    const int tstep = dir ? -1 : 1;
    const int tt0   = dir ? (T_TOTAL - 1) : 0;

    const ptrdiff_t gpstep = (ptrdiff_t)tstep * (B_TOTAL * NG);
    const uint32_t* gp = gbuf + (size_t)(tt0 * B_TOTAL + bs) * NG + dir * (2 * H) + 2 * j;

    __half* op = nullptr;
    ptrdiff_t opstep = 0;
    if constexpr (STORE_ALL) {
        op = outact + (size_t)(tt0 * B_TOTAL + bs) * (2 * H) + dir * H + j;
        opstep = (ptrdiff_t)tstep * (B_TOTAL * 2 * H);
    }

    uint2 qb[4];
#pragma unroll
    for (int s = 0; s < 3; ++s) {     // T >= 3
        qb[s] = *(const uint2*)gp;
        gp += gpstep;
    }

    float c = 0.0f;
    float hlast = 0.0f;
    ((__half*)&hsm[g][0])[j] = __float2half(0.0f);
    wavebar();

    auto step = [&](const uint2 qc, uint2& qn, bool pf) {
        uint32_t hd[NH];
#pragma unroll
        for (int k = 0; k < NH; ++k) hd[k] = hsm[g][k];

        f16x2 lo = __builtin_bit_cast(f16x2, qc.x);
        f16x2 hi = __builtin_bit_cast(f16x2, qc.y);
        float a0 = (float)lo.x, a1 = (float)lo.y;
        float a2 = (float)hi.x, a3 = (float)hi.y;

        if (pf) { qn = *(const uint2*)gp; gp += gpstep; }

#pragma unroll
        for (int k = 0; k < NH; ++k) {
            a0 = dot2acc(hd[k], whh2[0][k], a0);
            a1 = dot2acc(hd[k], whh2[1][k], a1);
            a2 = dot2acc(hd[k], whh2[2][k], a2);
            a3 = dot2acc(hd[k], whh2[3][k], a3);
        }
        const float iv = sigm_(a0);
        const float fv = sigm_(a1);
        const float gv = tanh_(a2);
        const float ov = sigm_(a3);
        c = __builtin_fmaf(fv, c, iv * gv);
        const float h = ov * tanh_(c);
        ((__half*)&hsm[g][0])[j] = __float2half(h);
        wavebar();
        if constexpr (STORE_ALL) {
            if (valid) *op = __float2half(h);
            op += opstep;
        } else {
            hlast = h;
        }
    };

    for (int t = 0; t < T_TOTAL; t += 4) {
        step(qb[0], qb[3], t + 3 < T_TOTAL);
        step(qb[1], qb[0], t + 4 < T_TOTAL);
        step(qb[2], qb[1], t + 5 < T_TOTAL);
        step(qb[3], qb[2], t + 6 < T_TOTAL);
    }

    if constexpr (!STORE_ALL) {
        if (valid) lasth[b * H + j] = hlast;
    }
}

// ======================= FALLBACK PATH (round-4, ws-tight) =======================
template <int DIN, int H, bool LAYER1, bool STORE_ALL>
__global__ void __launch_bounds__(64, 1) lstm_scan(
    const float* __restrict__ x,
    const __half* __restrict__ inbuf,
    const float* __restrict__ wihf, const float* __restrict__ whhf,
    const float* __restrict__ bihf, const float* __restrict__ bhhf,
    const float* __restrict__ wihb, const float* __restrict__ whhb,
    const float* __restrict__ bihb, const float* __restrict__ bhhb,
    __half* __restrict__ outbuf,
    float* __restrict__ lasth)
{
    constexpr int GPW   = 64 / H;
    constexpr int ND    = DIN / 2;
    constexpr int NH    = H / 2;
    constexpr int HS_DW = (H == 20) ? 12 : 8;

    const int dir  = blockIdx.y;
    const int lane = threadIdx.x;
    const int g    = lane / H;
    const int j    = lane - g * H;
    const int b    = blockIdx.x * GPW + g;
    const bool valid = (g < GPW) && (b < B_TOTAL);
    const int bs   = valid ? b : (B_TOTAL - 1);

    const float* w_ih = dir ? wihb : wihf;
    const float* w_hh = dir ? whhb : whhf;
    const float* b_ih = dir ? bihb : bihf;
    const float* b_hh = dir ? bhhb : bhhf;

    __shared__ uint32_t hsm[GPW + 1][HS_DW];

    f16x2 wih2[4][ND];
    f16x2 whh2[4][NH];
    float bias[4];
#pragma unroll
    for (int q = 0; q < 4; ++q) {
        const int r = q * H + j;
#pragma unroll
        for (int d = 0; d < ND; ++d) {
            f16x2 t;
            t.x = (_Float16)w_ih[r * DIN + 2 * d];
            t.y = (_Float16)w_ih[r * DIN + 2 * d + 1];
            wih2[q][d] = t;
        }
#pragma unroll
        for (int k = 0; k < NH; ++k) {
            f16x2 t;
            t.x = (_Float16)w_hh[r * H + 2 * k];
            t.y = (_Float16)w_hh[r * H + 2 * k + 1];
            whh2[q][k] = t;
        }
        bias[q] = b_ih[r] + b_hh[r];
    }

    const int tstep = dir ? -1 : 1;
    int tt = dir ? (T_TOTAL - 1) : 0;

    __half* op = nullptr;
    ptrdiff_t opstep = 0;
    if constexpr (STORE_ALL) {
        op = outbuf + (size_t)tt * (B_TOTAL * 2 * H) + (size_t)bs * (2 * H) + dir * H + j;
        opstep = (ptrdiff_t)tstep * (B_TOTAL * 2 * H);
    }

    float c = 0.0f;
    float hlast = 0.0f;
    ((__half*)&hsm[g][0])[j] = __float2half(0.0f);
    wavebar();

    auto tail = [&](const uint32_t* hd, float a0, float a1, float a2, float a3) {
#pragma unroll
        for (int k = 0; k < NH; ++k) {
            a0 = dot2acc(hd[k], whh2[0][k], a0);
            a1 = dot2acc(hd[k], whh2[1][k], a1);
            a2 = dot2acc(hd[k], whh2[2][k], a2);
            a3 = dot2acc(hd[k], whh2[3][k], a3);
        }
        const float iv = sigm_(a0);
        const float fv = sigm_(a1);
        const float gv = tanh_(a2);
        const float ov = sigm_(a3);
        c = __builtin_fmaf(fv, c, iv * gv);
        const float h = ov * tanh_(c);
        ((__half*)&hsm[g][0])[j] = __float2half(h);
        wavebar();
        if constexpr (STORE_ALL) {
            if (valid) *op = __float2half(h);
            op += opstep;
        } else {
            hlast = h;
        }
        tt += tstep;
    };

    if constexpr (LAYER1) {
        const float* xrow = x + (size_t)bs * (T_TOTAL * 8);
        uint32_t xcur[4], xlag[4];
        {
            const float4* p = (const float4*)(xrow + (size_t)tt * 8);
            float4 u0 = p[0], u1 = p[1];
            xcur[0] = packf2(u0.x, u0.y); xcur[1] = packf2(u0.z, u0.w);
            xcur[2] = packf2(u1.x, u1.y); xcur[3] = packf2(u1.z, u1.w);
            if (dir) {
                const float4* q = (const float4*)(xrow + (size_t)(tt - 1) * 8);
                float4 v0 = q[0], v1 = q[1];
                xlag[0] = packf2(v0.x, v0.y); xlag[1] = packf2(v0.z, v0.w);
                xlag[2] = packf2(v1.x, v1.y); xlag[3] = packf2(v1.z, v1.w);
            } else {
#pragma unroll
                for (int d = 0; d < 4; ++d) xlag[d] = 0u;
            }
        }

        for (int t = 0; t < T_TOTAL; ++t) {
            uint32_t hd[NH];
#pragma unroll
            for (int k = 0; k < NH; ++k) hd[k] = hsm[g][k];

            float a0 = bias[0], a1 = bias[1], a2 = bias[2], a3 = bias[3];
#pragma unroll
            for (int d = 0; d < 4; ++d) {
                a0 = dot2acc(xcur[d], wih2[0][d], a0);
                a1 = dot2acc(xcur[d], wih2[1][d], a1);
                a2 = dot2acc(xcur[d], wih2[2][d], a2);
                a3 = dot2acc(xcur[d], wih2[3][d], a3);
            }
#pragma unroll
            for (int d = 0; d < 4; ++d) {
                a0 = dot2acc(xlag[d], wih2[0][4 + d], a0);
                a1 = dot2acc(xlag[d], wih2[1][4 + d], a1);
                a2 = dot2acc(xlag[d], wih2[2][4 + d], a2);
                a3 = dot2acc(xlag[d], wih2[3][4 + d], a3);
            }

            const int li = dir ? (tt - 2) : (tt + 1);
            const bool ld = (li >= 0) && (li < T_TOTAL);
            float4 n0 = {0, 0, 0, 0}, n1 = {0, 0, 0, 0};
            if (ld) {
                const float4* p = (const float4*)(xrow + (size_t)li * 8);
                n0 = p[0];
                n1 = p[1];
            }

            tail(hd, a0, a1, a2, a3);

            uint32_t np[4] = {packf2(n0.x, n0.y), packf2(n0.z, n0.w),
                              packf2(n1.x, n1.y), packf2(n1.z, n1.w)};
            if (dir == 0) {
#pragma unroll
                for (int d = 0; d < 4; ++d) { xlag[d] = xcur[d]; xcur[d] = np[d]; }
            } else {
#pragma unroll
                for (int d = 0; d < 4; ++d) {
                    xcur[d] = xlag[d];
                    xlag[d] = ld ? np[d] : 0u;
                }
            }
        }
    } else {
        const ptrdiff_t ipstep = (ptrdiff_t)tstep * (B_TOTAL * ND);
        const uint32_t* ip = (const uint32_t*)inbuf + (size_t)tt * (B_TOTAL * ND) + (size_t)bs * ND;

        uint32_t xb[4][ND];
#pragma unroll
        for (int s = 0; s < 3; ++s) {
#pragma unroll
            for (int d = 0; d < ND; ++d) xb[s][d] = ip[d];
            ip += ipstep;
        }

        auto stp = [&](const uint32_t* xc, uint32_t* xn, bool pf) {
            uint32_t hd[NH];
#pragma unroll
            for (int k = 0; k < NH; ++k) hd[k] = hsm[g][k];

            float a0 = bias[0], a1 = bias[1], a2 = bias[2], a3 = bias[3];
#pragma unroll
            for (int d = 0; d < ND; ++d) {
                a0 = dot2acc(xc[d], wih2[0][d], a0);
                a1 = dot2acc(xc[d], wih2[1][d], a1);
                a2 = dot2acc(xc[d], wih2[2][d], a2);
                a3 = dot2acc(xc[d], wih2[3][d], a3);
            }
            if (pf) {
#pragma unroll
                for (int d = 0; d < ND; ++d) xn[d] = ip[d];
                ip += ipstep;
            }
            tail(hd, a0, a1, a2, a3);
        };

        for (int t = 0; t < T_TOTAL; t += 4) {
            stp(xb[0], xb[3], t + 3 < T_TOTAL);
            stp(xb[1], xb[0], t + 4 < T_TOTAL);
            stp(xb[2], xb[1], t + 5 < T_TOTAL);
            stp(xb[3], xb[2], t + 6 < T_TOTAL);
        }
    }

    if constexpr (!STORE_ALL) {
        if (valid) lasth[b * H + j] = hlast;
    }
}

// L4 backward needed only at t=T-1 (single step from zero state) + FC + sigmoid.
__global__ void final_kernel(const __half* __restrict__ l3out,  // [T][B][20] f16
                             const float* __restrict__ hf4,     // [B][10]
                             const float* __restrict__ w_ih,    // w4b_ih [40][20]
                             const float* __restrict__ b_ih,
                             const float* __restrict__ b_hh,
                             const float* __restrict__ fc_w,    // [20]
                             const float* __restrict__ fc_b,
                             float* __restrict__ out)           // [B]
{
    const int b = blockIdx.x * blockDim.x + threadIdx.x;
    if (b >= B_TOTAL) return;

    float in4[20];
    const __half* p = l3out + (size_t)(T_TOTAL - 1) * (B_TOTAL * 20) + (size_t)b * 20;
#pragma unroll
    for (int i = 0; i < 20; ++i) in4[i] = __half2float(p[i]);

    float z = fc_b[0];
#pragma unroll
    for (int k = 0; k < 10; ++k) z += fc_w[k] * hf4[b * 10 + k];

#pragma unroll
    for (int k = 0; k < 10; ++k) {
        float gi = b_ih[k]      + b_hh[k];
        float gg = b_ih[20 + k] + b_hh[20 + k];
        float go = b_ih[30 + k] + b_hh[30 + k];
#pragma unroll
        for (int i = 0; i < 20; ++i) {
            const float xi = in4[i];
            gi += w_ih[k * 20 + i]        * xi;
            gg += w_ih[(20 + k) * 20 + i] * xi;
            go += w_ih[(30 + k) * 20 + i] * xi;
        }
        const float cc = sigm_(gi) * tanh_(gg);
        const float hb = sigm_(go) * tanh_(cc);
        z += fc_w[10 + k] * hb;
    }
    out[b] = sigm_(z);
}

extern "C" void kernel_launch(void* const* d_in, const int* in_sizes, int n_in,
                              void* d_out, int out_size, void* d_ws, size_t ws_size,
                              hipStream_t stream) {
    const float* x = (const float*)d_in[0];
    auto W = [&](int li, int dr, int k) -> const float* {
        return (const float*)d_in[1 + (li - 1) * 8 + dr * 4 + k];
    };
    const float* fc_w = (const float*)d_in[33];
    const float* fc_b = (const float*)d_in[34];
    float* out = (float*)d_out;

    const size_t TB = (size_t)T_TOTAL * B_TOTAL;
    const size_t G_BYTES = TB * 80 * 4;      // 320 MiB: max gate buf (NG=80 dw)
    const size_t A_BYTES = TB * 40 * 2;      // 80 MiB: act buf ([T][B][40] f16 max)
    const size_t H4_BYTES = (size_t)B_TOTAL * 10 * 4;

    if (ws_size >= G_BYTES + A_BYTES + H4_BYTES) {
        // -------- fast path: hoisted gate pre-GEMMs + slim scans --------
        uint32_t* G = (uint32_t*)d_ws;
        __half* A = (__half*)((char*)d_ws + G_BYTES);
        float* hf4 = (float*)((char*)d_ws + G_BYTES + A_BYTES);

        // L1: D=16 (x+lag), H=20, 2 dirs
        gates_gemm<16, 20, 2, true><<<2048, 320, 0, stream>>>(
            x, nullptr,
            W(1,0,0), W(1,0,2), W(1,0,3),
            W(1,1,0), W(1,1,2), W(1,1,3), G);
        lstm_scan2<20, 2, true><<<dim3(342, 2, 1), 64, 0, stream>>>(
            G, W(1,0,1), W(1,1,1), A, nullptr);

        // L2: D=40, H=20
        gates_gemm<40, 20, 2, false><<<2048, 320, 0, stream>>>(
            nullptr, A,
            W(2,0,0), W(2,0,2), W(2,0,3),
            W(2,1,0), W(2,1,2), W(2,1,3), G);
        lstm_scan2<20, 2, true><<<dim3(342, 2, 1), 64, 0, stream>>>(
            G, W(2,0,1), W(2,1,1), A, nullptr);

        // L3: D=40, H=10
        gates_gemm<40, 10, 2, false><<<2048, 320, 0, stream>>>(
            nullptr, A,
            W(3,0,0), W(3,0,2), W(3,0,3),
            W(3,1,0), W(3,1,2), W(3,1,3), G);
        lstm_scan2<10, 2, true><<<dim3(171, 2, 1), 64, 0, stream>>>(
            G, W(3,0,1), W(3,1,1), A, nullptr);

        // L4 fwd only: D=20, H=10
        gates_gemm<20, 10, 1, false><<<2048, 320, 0, stream>>>(
            nullptr, A,
            W(4,0,0), W(4,0,2), W(4,0,3),
            W(4,0,0), W(4,0,2), W(4,0,3), G);
        lstm_scan2<10, 1, false><<<dim3(171, 1, 1), 64, 0, stream>>>(
            G, W(4,0,1), W(4,0,1), nullptr, hf4);

        final_kernel<<<dim3(4, 1, 1), 256, 0, stream>>>(
            A, hf4, W(4,1,0), W(4,1,2), W(4,1,3), fc_w, fc_b, out);
    } else {
        // -------- fallback (round-4): fused scans, 160 MiB ws --------
        __half* buf0 = (__half*)d_ws;
        __half* buf1 = buf0 + TB * 40;
        float* hf4 = (float*)(buf1 + TB * 40);

        lstm_scan<16, 20, true, true><<<dim3(342, 2, 1), 64, 0, stream>>>(
            x, nullptr,
            W(1,0,0), W(1,0,1), W(1,0,2), W(1,0,3),
            W(1,1,0), W(1,1,1), W(1,1,2), W(1,1,3),
            buf0, nullptr);
        lstm_scan<40, 20, false, true><<<dim3(342, 2, 1), 64, 0, stream>>>(
            nullptr, buf0,
            W(2,0,0), W(2,0,1), W(2,0,2), W(2,0,3),
            W(2,1,0), W(2,1,1), W(2,1,2), W(2,1,3),
            buf1, nullptr);
        lstm_scan<40, 10, false, true><<<dim3(171, 2, 1), 64, 0, stream>>>(
            nullptr, buf1,
            W(3,0,0), W(3,0,1), W(3,0,2), W(3,0,3),
            W(3,1,0), W(3,1,1), W(3,1,2), W(3,1,3),
            buf0, nullptr);
        lstm_scan<20, 10, false, false><<<dim3(171, 1, 1), 64, 0, stream>>>(
            nullptr, buf0,
            W(4,0,0), W(4,0,1), W(4,0,2), W(4,0,3),
            W(4,0,0), W(4,0,1), W(4,0,2), W(4,0,3),
            nullptr, hf4);
        final_kernel<<<dim3(4, 1, 1), 256, 0, stream>>>(
            buf0, hf4, W(4,1,0), W(4,1,2), W(4,1,3), fc_w, fc_b, out);
    }
}